// Round 3
// baseline (335.527 us; speedup 1.0000x reference)
//
#include <hip/hip_runtime.h>

// CausalSelfAttention: B=4, S=2048, D=1024, H=16, HS=64
// x @ w_qkv + b -> qkv ; per-head causal attn (scale 1/sqrt(H)=0.25) ; @ w_proj + b
// bf16 MFMA everywhere, fp32 accumulate.

typedef unsigned short u16;
typedef short bf16x8 __attribute__((ext_vector_type(8)));
typedef unsigned short u16x8 __attribute__((ext_vector_type(8)));
typedef float f32x4 __attribute__((ext_vector_type(4)));

#define S_LEN 2048
#define DMODEL 1024
#define NHEAD 16
#define MROWS 8192  // B*S

// 0.25 (1/sqrt(H)) * log2(e): softmax in exp2 domain
#define SCALE_LOG2E 0.36067376022224085f

__device__ __forceinline__ u16 f2bf(float f) {
  union { float f; unsigned u; } c; c.f = f;
  unsigned u = c.u;
  u += 0x7fffu + ((u >> 16) & 1u);  // RNE
  return (u16)(u >> 16);
}

__device__ __forceinline__ float exp2_fast(float x) {
  float r; asm("v_exp_f32 %0, %1" : "=v"(r) : "v"(x)); return r;
}

__device__ __forceinline__ unsigned cvtpk_bf16(float a, float b) {
  unsigned r;
  asm("v_cvt_pk_bf16_f32 %0, %1, %2" : "=v"(r) : "v"(a), "v"(b));
  return r;
}

__device__ __forceinline__ f32x4 mfma16(bf16x8 a, bf16x8 b, f32x4 c) {
  return __builtin_amdgcn_mfma_f32_16x16x32_bf16(a, b, c, 0, 0, 0);
}

__device__ __forceinline__ void gload_lds16(const void* g, void* l) {
  __builtin_amdgcn_global_load_lds((__attribute__((address_space(1))) void*)g,
                                   (__attribute__((address_space(3))) void*)l,
                                   16, 0, 0);
}

// ---------------- conversion kernels ----------------
__global__ void k_f32_to_bf16(const float* __restrict__ in, u16* __restrict__ out, int n) {
  int i = (blockIdx.x * 256 + threadIdx.x) * 4;
  if (i < n) {
    float4 v = *reinterpret_cast<const float4*>(in + i);
    ushort4 o;
    o.x = f2bf(v.x); o.y = f2bf(v.y); o.z = f2bf(v.z); o.w = f2bf(v.w);
    *reinterpret_cast<ushort4*>(out + i) = o;
  }
}

// w[K][N] fp32 -> wt[N][K] bf16
__global__ void k_transpose_to_bf16(const float* __restrict__ in, u16* __restrict__ out,
                                    int K, int N) {
  __shared__ float t[32][33];
  int n0 = blockIdx.x * 32, k0 = blockIdx.y * 32;
  int tx = threadIdx.x & 31, ty = threadIdx.x >> 5;  // 32 x 8
#pragma unroll
  for (int i = 0; i < 32; i += 8)
    t[ty + i][tx] = in[(size_t)(k0 + ty + i) * N + n0 + tx];
  __syncthreads();
#pragma unroll
  for (int i = 0; i < 32; i += 8)
    out[(size_t)(n0 + ty + i) * K + k0 + tx] = f2bf(t[tx][ty + i]);
}

// V part of qkv -> Vt[(b*16+h)*64 + d][s within b]  (bf16)
__global__ void k_vt(const u16* __restrict__ qkv, u16* __restrict__ vt) {
  __shared__ u16 t[64][65];
  const int tid = threadIdx.x;
  const int s0 = blockIdx.x * 64;
  const int bh = blockIdx.y, b = bh >> 4, h = bh & 15;
  const size_t inbase = (size_t)b * S_LEN * 3072 + 2048 + h * 64;
  for (int i = tid; i < 512; i += 256) {
    int row = i >> 3, c = i & 7;
    u16x8 v = *reinterpret_cast<const u16x8*>(qkv + inbase + (size_t)(s0 + row) * 3072 + c * 8);
#pragma unroll
    for (int j = 0; j < 8; ++j) t[row][c * 8 + j] = v[j];
  }
  __syncthreads();
  const size_t outbase = (size_t)bh * 64 * S_LEN + s0;
  for (int i = tid; i < 512; i += 256) {
    int d = i >> 3, c = i & 7;
    u16x8 o;
#pragma unroll
    for (int j = 0; j < 8; ++j) o[j] = t[c * 8 + j][d];
    *reinterpret_cast<u16x8*>(vt + outbase + (size_t)d * S_LEN + c * 8) = o;
  }
}

// ---------------- GEMM: C[M][N] = A[M][K] * Bt[N][K]^T + bias ----------------
template <bool OUT_BF16>
__global__ __launch_bounds__(256) void k_gemm_bt(const u16* __restrict__ A,
                                                 const u16* __restrict__ Bt,
                                                 const float* __restrict__ bias,
                                                 u16* __restrict__ outb,
                                                 float* __restrict__ outf,
                                                 int N, int K) {
  __shared__ u16 As[128 * 64];
  __shared__ u16 Bs[128 * 64];
  const int tid = threadIdx.x;
  const int lane = tid & 63, wave = tid >> 6;
  const int wm = wave >> 1, wn = wave & 1;
  const int lr = lane & 15, lk = lane >> 4;
  const int m0 = blockIdx.x * 128, n0 = blockIdx.y * 128;

  f32x4 zero4 = {0.f, 0.f, 0.f, 0.f};
  f32x4 acc[4][4];
#pragma unroll
  for (int m = 0; m < 4; ++m)
#pragma unroll
    for (int n = 0; n < 4; ++n) acc[m][n] = zero4;

  const int nkt = K >> 6;
  for (int kt = 0; kt < nkt; ++kt) {
    const u16* Ag = A + (size_t)m0 * K + kt * 64;
    const u16* Bg = Bt + (size_t)n0 * K + kt * 64;
#pragma unroll
    for (int j = 0; j < 4; ++j) {
      int chunk = j * 4 + wave;
      int row = chunk * 8 + (lane >> 3);
      int cole = (lane & 7) * 8;
      gload_lds16(Ag + (size_t)row * K + cole, &As[chunk * 512]);
      gload_lds16(Bg + (size_t)row * K + cole, &Bs[chunk * 512]);
    }
    __syncthreads();
#pragma unroll
    for (int ks = 0; ks < 2; ++ks) {
      bf16x8 af[4], bfr[4];
#pragma unroll
      for (int m = 0; m < 4; ++m)
        af[m] = *reinterpret_cast<const bf16x8*>(&As[(wm * 64 + m * 16 + lr) * 64 + ks * 32 + lk * 8]);
#pragma unroll
      for (int n = 0; n < 4; ++n)
        bfr[n] = *reinterpret_cast<const bf16x8*>(&Bs[(wn * 64 + n * 16 + lr) * 64 + ks * 32 + lk * 8]);
#pragma unroll
      for (int m = 0; m < 4; ++m)
#pragma unroll
        for (int n = 0; n < 4; ++n) acc[m][n] = mfma16(af[m], bfr[n], acc[m][n]);
    }
    __syncthreads();
  }

#pragma unroll
  for (int n = 0; n < 4; ++n) {
    int col = n0 + wn * 64 + n * 16 + lr;
    float bv = bias[col];
#pragma unroll
    for (int m = 0; m < 4; ++m) {
#pragma unroll
      for (int r = 0; r < 4; ++r) {
        int row = m0 + wm * 64 + m * 16 + lk * 4 + r;
        float v = acc[m][n][r] + bv;
        if (OUT_BF16)
          outb[(size_t)row * N + col] = f2bf(v);
        else
          outf[(size_t)row * N + col] = v;
      }
    }
  }
}

// ---------------- flash attention v3 ----------------
// Swapped QK^T (mfma(K,Q)): lane holds 16 scores of ONE q-row (q = lane&15).
// In-lane row reduce + 2 butterflies. P packed via cvt_pk -> ds_write_b64.
// Load balance: wave handles 16 rows of tile qb (lo) + 16 rows of tile 31-qb (hi);
// every wave in the grid does ~33 uniform iterations. No __syncthreads.
__global__ __launch_bounds__(256, 4) void k_attn3(const u16* __restrict__ qkv,
                                                  const u16* __restrict__ vt,
                                                  u16* __restrict__ ao) {
  __shared__ unsigned char PsB[4][4096];  // per-wave: 2 m-groups x 16 rows x 128B
  const int tid = threadIdx.x;
  const int lane = tid & 63, wave = tid >> 6;
  const int lr = lane & 15, lk = lane >> 4;
  const int gid = blockIdx.x;
  const int bh = gid & 63, qb = gid >> 6;
  const int b = bh >> 4, h = bh & 15;
  const size_t rowb = (size_t)b * S_LEN * 3072;
  const int qcol = h * 64, kcol = 1024 + h * 64;
  unsigned char* myP = PsB[wave];

  const int qlo0 = qb * 64 + wave * 16;          // m=0 row base
  const int qhi0 = 1984 - qb * 64 + wave * 16;   // m=1 row base (mirrored)

  // Q fragments direct from global (L2-hot)
  bf16x8 qf[2][2];
#pragma unroll
  for (int ks = 0; ks < 2; ++ks) {
    qf[0][ks] = *reinterpret_cast<const bf16x8*>(
        qkv + rowb + (size_t)(qlo0 + lr) * 3072 + qcol + ks * 32 + lk * 8);
    qf[1][ks] = *reinterpret_cast<const bf16x8*>(
        qkv + rowb + (size_t)(qhi0 + lr) * 3072 + qcol + ks * 32 + lk * 8);
  }

  // per-lane K/V base pointers (strength-reduced)
  const u16* kbase = qkv + rowb + kcol + (size_t)lr * 3072 + lk * 8;
  const u16* vbase = vt + (size_t)bh * 64 * S_LEN + (size_t)lr * S_LEN + lk * 8;

  f32x4 zero4 = {0.f, 0.f, 0.f, 0.f};
  f32x4 oacc[2][4];
#pragma unroll
  for (int m = 0; m < 2; ++m)
#pragma unroll
    for (int n = 0; n < 4; ++n) oacc[m][n] = zero4;
  float m_i[2] = {-INFINITY, -INFINITY};  // running max (exp2 domain) for q = lr
  float l_i[2] = {0.f, 0.f};

  const int ktlo = qb, ktmax = 31 - qb;

  // softmax for m-group M from scores scM; MASKED: diagonal tile
#define SOFTMAX_M(scM, M, MASKED)                                                     \
  {                                                                                   \
    float s_[4][4];                                                                   \
    float mx_ = -INFINITY;                                                            \
    _Pragma("unroll") for (int c = 0; c < 4; ++c)                                     \
        _Pragma("unroll") for (int r = 0; r < 4; ++r) {                               \
      float v_ = scM[c][r] * SCALE_LOG2E;                                             \
      if (MASKED && (c * 16 + lk * 4 + r) > (wave * 16 + lr)) v_ = -INFINITY;         \
      s_[c][r] = v_;                                                                  \
      mx_ = fmaxf(mx_, v_);                                                           \
    }                                                                                 \
    mx_ = fmaxf(mx_, __shfl_xor(mx_, 16, 64));                                        \
    mx_ = fmaxf(mx_, __shfl_xor(mx_, 32, 64));                                        \
    float mnew_ = fmaxf(m_i[M], mx_);                                                 \
    float corr_ = exp2_fast(m_i[M] - mnew_);                                          \
    m_i[M] = mnew_;                                                                   \
    float rsum_ = 0.f;                                                                \
    _Pragma("unroll") for (int c = 0; c < 4; ++c) {                                   \
      float p0_ = exp2_fast(s_[c][0] - mnew_);                                        \
      float p1_ = exp2_fast(s_[c][1] - mnew_);                                        \
      float p2_ = exp2_fast(s_[c][2] - mnew_);                                        \
      float p3_ = exp2_fast(s_[c][3] - mnew_);                                        \
      rsum_ += (p0_ + p1_) + (p2_ + p3_);                                             \
      uint2 w_;                                                                       \
      w_.x = cvtpk_bf16(p0_, p1_);                                                    \
      w_.y = cvtpk_bf16(p2_, p3_);                                                    \
      *reinterpret_cast<uint2*>(myP + (M * 16 + lr) * 128 +                           \
                                (((c * 32 + lk * 8)) ^ ((lr & 7) << 4))) = w_;        \
    }                                                                                 \
    rsum_ += __shfl_xor(rsum_, 16, 64);                                               \
    rsum_ += __shfl_xor(rsum_, 32, 64);                                               \
    l_i[M] = l_i[M] * corr_ + rsum_;                                                  \
    float c0_ = __shfl(corr_, (lane & 48) | (lk * 4 + 0), 64);                        \
    float c1_ = __shfl(corr_, (lane & 48) | (lk * 4 + 1), 64);                        \
    float c2_ = __shfl(corr_, (lane & 48) | (lk * 4 + 2), 64);                        \
    float c3_ = __shfl(corr_, (lane & 48) | (lk * 4 + 3), 64);                        \
    f32x4 cv_ = {c0_, c1_, c2_, c3_};                                                 \
    _Pragma("unroll") for (int n = 0; n < 4; ++n) oacc[M][n] *= cv_;                  \
  }

#define ATTN_ITER(KT, DO0, MASK0, MASK1)                                              \
  {                                                                                   \
    const u16* kp_ = kbase + (size_t)(KT) * 64 * 3072;                                \
    const u16* vp_ = vbase + (KT) * 64;                                               \
    f32x4 sc0[4], sc1[4];                                                             \
    _Pragma("unroll") for (int c = 0; c < 4; ++c) { sc0[c] = zero4; sc1[c] = zero4; } \
    _Pragma("unroll") for (int ks = 0; ks < 2; ++ks)                                  \
        _Pragma("unroll") for (int c = 0; c < 4; ++c) {                               \
      bf16x8 kf_ = *reinterpret_cast<const bf16x8*>(kp_ + (size_t)(c * 16) * 3072 +   \
                                                    ks * 32);                         \
      if (DO0) sc0[c] = mfma16(kf_, qf[0][ks], sc0[c]);                               \
      sc1[c] = mfma16(kf_, qf[1][ks], sc1[c]);                                        \
    }                                                                                 \
    bf16x8 vb_[2][4];                                                                 \
    _Pragma("unroll") for (int n = 0; n < 4; ++n)                                     \
        vb_[0][n] = *reinterpret_cast<const bf16x8*>(vp_ + (size_t)(n * 16) * S_LEN); \
    if (DO0) SOFTMAX_M(sc0, 0, MASK0);                                                \
    _Pragma("unroll") for (int n = 0; n < 4; ++n)                                     \
        vb_[1][n] = *reinterpret_cast<const bf16x8*>(vp_ + (size_t)(n * 16) * S_LEN + 32); \
    SOFTMAX_M(sc1, 1, MASK1);                                                         \
    _Pragma("unroll") for (int m = 0; m < 2; ++m) {                                   \
      if (m == 0 && !DO0) continue;                                                   \
      _Pragma("unroll") for (int ks = 0; ks < 2; ++ks) {                              \
        bf16x8 pa_ = *reinterpret_cast<const bf16x8*>(                                \
            myP + (m * 16 + lr) * 128 + ((ks * 64 + lk * 16) ^ ((lr & 7) << 4)));     \
        _Pragma("unroll") for (int n = 0; n < 4; ++n)                                 \
            oacc[m][n] = mfma16(pa_, vb_[ks][n], oacc[m][n]);                         \
      }                                                                               \
    }                                                                                 \
  }

  // Phase A: both m-groups, kt = 0..qb (mask m0 at kt==qb)
  for (int kt = 0; kt < ktlo; ++kt) ATTN_ITER(kt, 1, 0, 0);
  ATTN_ITER(ktlo, 1, 1, 0);
  // Phase B: hi group only, kt = qb+1..31-qb (mask m1 at kt==ktmax)
  for (int kt = ktlo + 1; kt < ktmax; ++kt) ATTN_ITER(kt, 0, 0, 0);
  ATTN_ITER(ktmax, 0, 0, 1);

#undef ATTN_ITER
#undef SOFTMAX_M

  // ---- epilogue: O[q][d] with q = base_m + lk*4+r, d = h*64 + n*16 + lr ----
#pragma unroll
  for (int m = 0; m < 2; ++m) {
    const int base = (m == 0) ? qlo0 : qhi0;
    float iv[4];
#pragma unroll
    for (int r = 0; r < 4; ++r)
      iv[r] = 1.f / __shfl(l_i[m], (lane & 48) | (lk * 4 + r), 64);
#pragma unroll
    for (int n = 0; n < 4; ++n)
#pragma unroll
      for (int r = 0; r < 4; ++r) {
        int row = base + lk * 4 + r;
        int col = h * 64 + n * 16 + lr;
        ao[((size_t)b * S_LEN + row) * DMODEL + col] = f2bf(oacc[m][n][r] * iv[r]);
      }
  }
}

// ---------------- launch ----------------
extern "C" void kernel_launch(void* const* d_in, const int* in_sizes, int n_in,
                              void* d_out, int out_size, void* d_ws, size_t ws_size,
                              hipStream_t stream) {
  const float* x = (const float*)d_in[0];
  const float* wqkv = (const float*)d_in[1];
  const float* bqkv = (const float*)d_in[2];
  const float* wproj = (const float*)d_in[3];
  const float* bproj = (const float*)d_in[4];
  float* out = (float*)d_out;

  char* ws = (char*)d_ws;
  u16* Xb     = (u16*)(ws);                       // [8192][1024] bf16, 16 MiB
  u16* Wqkvt  = (u16*)(ws + (size_t)16777216);    // [3072][1024] bf16,  6 MiB
  u16* Wprojt = (u16*)(ws + (size_t)23068672);    // [1024][1024] bf16,  2 MiB
  u16* QKVb   = (u16*)(ws + (size_t)25165824);    // [8192][3072] bf16, 48 MiB
  u16* AOb    = (u16*)(ws + (size_t)75497472);    // [8192][1024] bf16, 16 MiB
  u16* Vt     = Xb;  // reuse: Xb dead after GEMM1

  k_f32_to_bf16<<<MROWS * DMODEL / 4 / 256, 256, 0, stream>>>(x, Xb, MROWS * DMODEL);
  k_transpose_to_bf16<<<dim3(3072 / 32, 1024 / 32), 256, 0, stream>>>(wqkv, Wqkvt, 1024, 3072);
  k_transpose_to_bf16<<<dim3(1024 / 32, 1024 / 32), 256, 0, stream>>>(wproj, Wprojt, 1024, 1024);

  k_gemm_bt<true><<<dim3(MROWS / 128, 3072 / 128), 256, 0, stream>>>(
      Xb, Wqkvt, bqkv, QKVb, nullptr, 3072, 1024);

  k_vt<<<dim3(S_LEN / 64, 4 * NHEAD), 256, 0, stream>>>(QKVb, Vt);

  k_attn3<<<dim3(1024), 256, 0, stream>>>(QKVb, Vt, AOb);

  k_gemm_bt<false><<<dim3(MROWS / 128, DMODEL / 128), 256, 0, stream>>>(
      AOb, Wprojt, bproj, nullptr, out, DMODEL, 1024);
}

// Round 4
// 248.246 us; speedup vs baseline: 1.3516x; 1.3516x over previous
//
#include <hip/hip_runtime.h>

// CausalSelfAttention: B=4, S=2048, D=1024, H=16, HS=64
// bf16 MFMA everywhere, fp32 accumulate. Attention: LDS-staged K/V (dbuf,
// pre-swizzled global_load_lds), swapped QK^T, exp2 softmax, defer-max.

typedef unsigned short u16;
typedef short bf16x8 __attribute__((ext_vector_type(8)));
typedef unsigned short u16x8 __attribute__((ext_vector_type(8)));
typedef float f32x4 __attribute__((ext_vector_type(4)));

#define S_LEN 2048
#define DMODEL 1024
#define NHEAD 16
#define MROWS 8192  // B*S

// 0.25 (1/sqrt(H)) * log2(e)
#define SCALE_LOG2E 0.36067376022224085f
#define DEFER_THR 8.0f

__device__ __forceinline__ u16 f2bf(float f) {
  union { float f; unsigned u; } c; c.f = f;
  unsigned u = c.u;
  u += 0x7fffu + ((u >> 16) & 1u);  // RNE
  return (u16)(u >> 16);
}

__device__ __forceinline__ float exp2_fast(float x) {
  float r; asm("v_exp_f32 %0, %1" : "=v"(r) : "v"(x)); return r;
}

__device__ __forceinline__ unsigned cvtpk_bf16(float a, float b) {
  unsigned r;
  asm("v_cvt_pk_bf16_f32 %0, %1, %2" : "=v"(r) : "v"(a), "v"(b));
  return r;
}

__device__ __forceinline__ f32x4 mfma16(bf16x8 a, bf16x8 b, f32x4 c) {
  return __builtin_amdgcn_mfma_f32_16x16x32_bf16(a, b, c, 0, 0, 0);
}

__device__ __forceinline__ void gload_lds16(const void* g, void* l) {
  __builtin_amdgcn_global_load_lds((__attribute__((address_space(1))) void*)g,
                                   (__attribute__((address_space(3))) void*)l,
                                   16, 0, 0);
}

// ---------------- conversion kernels ----------------
__global__ void k_f32_to_bf16(const float* __restrict__ in, u16* __restrict__ out, int n) {
  int i = (blockIdx.x * 256 + threadIdx.x) * 4;
  if (i < n) {
    float4 v = *reinterpret_cast<const float4*>(in + i);
    ushort4 o;
    o.x = f2bf(v.x); o.y = f2bf(v.y); o.z = f2bf(v.z); o.w = f2bf(v.w);
    *reinterpret_cast<ushort4*>(out + i) = o;
  }
}

// w[K][N] fp32 -> wt[N][K] bf16
__global__ void k_transpose_to_bf16(const float* __restrict__ in, u16* __restrict__ out,
                                    int K, int N) {
  __shared__ float t[32][33];
  int n0 = blockIdx.x * 32, k0 = blockIdx.y * 32;
  int tx = threadIdx.x & 31, ty = threadIdx.x >> 5;  // 32 x 8
#pragma unroll
  for (int i = 0; i < 32; i += 8)
    t[ty + i][tx] = in[(size_t)(k0 + ty + i) * N + n0 + tx];
  __syncthreads();
#pragma unroll
  for (int i = 0; i < 32; i += 8)
    out[(size_t)(n0 + ty + i) * K + k0 + tx] = f2bf(t[tx][ty + i]);
}

// ---------------- GEMM: C[M][N] = A[M][K] * Bt[N][K]^T + bias ----------------
// MODE 1: fp32 out (stride N).  MODE 2: qkv-split: col<2048 -> qk[row*2048+col]
// (bf16); col>=2048 -> V transposed into vt[(b*16+h)*64+d][s] (bf16).
template <int MODE>
__global__ __launch_bounds__(256) void k_gemm_bt(const u16* __restrict__ A,
                                                 const u16* __restrict__ Bt,
                                                 const float* __restrict__ bias,
                                                 u16* __restrict__ outb,
                                                 float* __restrict__ outf,
                                                 u16* __restrict__ vtout,
                                                 int N, int K) {
  __shared__ u16 As[128 * 64];
  __shared__ u16 Bs[128 * 64];
  const int tid = threadIdx.x;
  const int lane = tid & 63, wave = tid >> 6;
  const int wm = wave >> 1, wn = wave & 1;
  const int lr = lane & 15, lk = lane >> 4;
  const int m0 = blockIdx.x * 128, n0 = blockIdx.y * 128;

  f32x4 zero4 = {0.f, 0.f, 0.f, 0.f};
  f32x4 acc[4][4];
#pragma unroll
  for (int m = 0; m < 4; ++m)
#pragma unroll
    for (int n = 0; n < 4; ++n) acc[m][n] = zero4;

  const int nkt = K >> 6;
  for (int kt = 0; kt < nkt; ++kt) {
    const u16* Ag = A + (size_t)m0 * K + kt * 64;
    const u16* Bg = Bt + (size_t)n0 * K + kt * 64;
#pragma unroll
    for (int j = 0; j < 4; ++j) {
      int chunk = j * 4 + wave;
      int row = chunk * 8 + (lane >> 3);
      int cole = (lane & 7) * 8;
      gload_lds16(Ag + (size_t)row * K + cole, &As[chunk * 512]);
      gload_lds16(Bg + (size_t)row * K + cole, &Bs[chunk * 512]);
    }
    __syncthreads();
#pragma unroll
    for (int ks = 0; ks < 2; ++ks) {
      bf16x8 af[4], bfr[4];
#pragma unroll
      for (int m = 0; m < 4; ++m)
        af[m] = *reinterpret_cast<const bf16x8*>(&As[(wm * 64 + m * 16 + lr) * 64 + ks * 32 + lk * 8]);
#pragma unroll
      for (int n = 0; n < 4; ++n)
        bfr[n] = *reinterpret_cast<const bf16x8*>(&Bs[(wn * 64 + n * 16 + lr) * 64 + ks * 32 + lk * 8]);
#pragma unroll
      for (int m = 0; m < 4; ++m)
#pragma unroll
        for (int n = 0; n < 4; ++n) acc[m][n] = mfma16(af[m], bfr[n], acc[m][n]);
    }
    __syncthreads();
  }

#pragma unroll
  for (int n = 0; n < 4; ++n) {
    int col = n0 + wn * 64 + n * 16 + lr;
    float bv = bias[col];
#pragma unroll
    for (int m = 0; m < 4; ++m) {
      int rowb = m0 + wm * 64 + m * 16 + lk * 4;
      if (MODE == 1) {
#pragma unroll
        for (int r = 0; r < 4; ++r)
          outf[(size_t)(rowb + r) * N + col] = acc[m][n][r] + bv;
      } else {
        if (col < 2048) {
#pragma unroll
          for (int r = 0; r < 4; ++r)
            outb[(size_t)(rowb + r) * 2048 + col] = f2bf(acc[m][n][r] + bv);
        } else {
          // V: vt[(b*16+h)*64 + d][s], s = row within head (consecutive r)
          int hh = (col >> 6) & 15, dd = col & 63;
          int bb = rowb >> 11, ss = rowb & 2047;
          ushort4 o;
          o.x = f2bf(acc[m][n][0] + bv);
          o.y = f2bf(acc[m][n][1] + bv);
          o.z = f2bf(acc[m][n][2] + bv);
          o.w = f2bf(acc[m][n][3] + bv);
          *reinterpret_cast<ushort4*>(
              vtout + ((size_t)(bb * 16 + hh) * 64 + dd) * 2048 + ss) = o;
        }
      }
    }
  }
}

// ---------------- flash attention v4 ----------------
// Block = 4 waves; wave owns 16 lo rows (tile qb) + 16 hi rows (tile 31-qb).
// K,V tiles (64x64) double-buffered in block LDS via global_load_lds with
// pre-swizzled source columns; swapped QK^T; exp2 softmax; defer-max.
__global__ __launch_bounds__(256, 4) void k_attn4(const u16* __restrict__ qk,
                                                  const u16* __restrict__ vt,
                                                  u16* __restrict__ ao) {
  __shared__ u16 Ks[2][4096];   // [row 0..63][64 cols], 128B rows, XOR-swizzled
  __shared__ u16 Vs[2][4096];   // [d 0..63][64 keys], swizzled
  __shared__ u16 Ps[4][1024];   // per-wave 16 q-rows x 64 keys, swizzled

  const int tid = threadIdx.x;
  const int lane = tid & 63, wave = tid >> 6;
  const int lr = lane & 15, lk = lane >> 4;
  const int gid = blockIdx.x;
  const int bh = gid & 63, qb = gid >> 6;
  const int b = bh >> 4, h = bh & 15;

  const int qlo0 = qb * 64 + wave * 16;
  const int qhi0 = 1984 - qb * 64 + wave * 16;
  const int ktmax = 31 - qb;

  // Q fragments (B-operand: lane holds Q[q = lr][k chunk])
  bf16x8 qf[2][2];
#pragma unroll
  for (int ks = 0; ks < 2; ++ks) {
    qf[0][ks] = *reinterpret_cast<const bf16x8*>(
        qk + ((size_t)b * S_LEN + qlo0 + lr) * 2048 + h * 64 + ks * 32 + lk * 8);
    qf[1][ks] = *reinterpret_cast<const bf16x8*>(
        qk + ((size_t)b * S_LEN + qhi0 + lr) * 2048 + h * 64 + ks * 32 + lk * 8);
  }

  // staging source bases (per-lane, pre-swizzled column)
  const int swzcol = 16 * ((lane & 7) ^ (lane >> 3));
  const char* kg = (const char*)qk + ((size_t)b * S_LEN) * 4096 + 2048 + h * 128 +
                   (size_t)(lane >> 3) * 4096 + swzcol;
  const char* vg = (const char*)vt + ((size_t)bh * 64 + (lane >> 3)) * 4096 + swzcol;

#define STAGE(BUF, KT)                                                        \
  {                                                                           \
    const char* kg_ = kg + (size_t)(KT) * 64 * 4096;                          \
    const char* vg_ = vg + (size_t)(KT) * 128;                                \
    gload_lds16(kg_ + (size_t)(wave * 8) * 4096, &Ks[BUF][wave * 512]);       \
    gload_lds16(kg_ + (size_t)((wave + 4) * 8) * 4096, &Ks[BUF][(wave + 4) * 512]); \
    gload_lds16(vg_ + (size_t)(wave * 8) * 4096, &Vs[BUF][wave * 512]);       \
    gload_lds16(vg_ + (size_t)((wave + 4) * 8) * 4096, &Vs[BUF][(wave + 4) * 512]); \
  }

  f32x4 zero4 = {0.f, 0.f, 0.f, 0.f};
  f32x4 oacc[2][4];
#pragma unroll
  for (int m = 0; m < 2; ++m)
#pragma unroll
    for (int n = 0; n < 4; ++n) oacc[m][n] = zero4;
  float m_i[2] = {-INFINITY, -INFINITY};  // exp2-domain running max for q = lr
  float l_i[2] = {0.f, 0.f};

  char* Pb = (char*)&Ps[wave][0];
  const int xr = (lr & 7) << 4;  // read/write XOR for row lr

  // softmax m-group M from scores sc (f32x4[4]); key idx = c*16+lk*4+r, q = lr
#define SOFTMAX_M(sc, M, MASKED)                                              \
  {                                                                           \
    float s_[4][4];                                                           \
    float mx_ = -INFINITY;                                                    \
    _Pragma("unroll") for (int c = 0; c < 4; ++c)                             \
        _Pragma("unroll") for (int r = 0; r < 4; ++r) {                       \
      float v_ = sc[c][r] * SCALE_LOG2E;                                      \
      if (MASKED && (c * 16 + lk * 4 + r) > (wave * 16 + lr)) v_ = -INFINITY; \
      s_[c][r] = v_;                                                          \
      mx_ = fmaxf(mx_, v_);                                                   \
    }                                                                         \
    mx_ = fmaxf(mx_, __shfl_xor(mx_, 16, 64));                                \
    mx_ = fmaxf(mx_, __shfl_xor(mx_, 32, 64));                                \
    if (__any(mx_ > m_i[M] + DEFER_THR)) {                                    \
      float mnew_ = fmaxf(m_i[M], mx_);                                       \
      float corr_ = exp2_fast(m_i[M] - mnew_);                                \
      m_i[M] = mnew_;                                                         \
      l_i[M] *= corr_;                                                        \
      float c0_ = __shfl(corr_, (lane & 48) | (lk * 4 + 0), 64);              \
      float c1_ = __shfl(corr_, (lane & 48) | (lk * 4 + 1), 64);              \
      float c2_ = __shfl(corr_, (lane & 48) | (lk * 4 + 2), 64);              \
      float c3_ = __shfl(corr_, (lane & 48) | (lk * 4 + 3), 64);              \
      f32x4 cv_ = {c0_, c1_, c2_, c3_};                                       \
      _Pragma("unroll") for (int n = 0; n < 4; ++n) oacc[M][n] *= cv_;        \
    }                                                                         \
    float rsum_ = 0.f;                                                        \
    _Pragma("unroll") for (int c = 0; c < 4; ++c) {                           \
      float p0_ = exp2_fast(s_[c][0] - m_i[M]);                               \
      float p1_ = exp2_fast(s_[c][1] - m_i[M]);                               \
      float p2_ = exp2_fast(s_[c][2] - m_i[M]);                               \
      float p3_ = exp2_fast(s_[c][3] - m_i[M]);                               \
      rsum_ += (p0_ + p1_) + (p2_ + p3_);                                     \
      uint2 w_;                                                               \
      w_.x = cvtpk_bf16(p0_, p1_);                                            \
      w_.y = cvtpk_bf16(p2_, p3_);                                            \
      *reinterpret_cast<uint2*>(Pb + lr * 128 + ((c * 32 + lk * 8) ^ xr)) = w_; \
    }                                                                         \
    rsum_ += __shfl_xor(rsum_, 16, 64);                                       \
    rsum_ += __shfl_xor(rsum_, 32, 64);                                       \
    l_i[M] += rsum_;                                                          \
  }

  // prologue
  STAGE(0, 0);
  __syncthreads();
  int buf = 0;

  for (int kt = 0; kt <= ktmax; ++kt) {
    if (kt < ktmax) STAGE(buf ^ 1, kt + 1);

    const char* Kb = (const char*)&Ks[buf][0];
    const char* Vb = (const char*)&Vs[buf][0];
    const bool do0 = (kt <= qb);
    const bool mask0 = (kt == qb), mask1 = (kt == ktmax);

    // QK^T (swapped): sc[c] rows = keys c*16.., cols = q
    f32x4 sc0[4], sc1[4];
#pragma unroll
    for (int c = 0; c < 4; ++c) { sc0[c] = zero4; sc1[c] = zero4; }
#pragma unroll
    for (int ks = 0; ks < 2; ++ks) {
      bf16x8 kf[4];
#pragma unroll
      for (int c = 0; c < 4; ++c)
        kf[c] = *reinterpret_cast<const bf16x8*>(
            Kb + (c * 16 + lr) * 128 + ((ks * 64 + lk * 16) ^ xr));
#pragma unroll
      for (int c = 0; c < 4; ++c) {
        sc1[c] = mfma16(kf[c], qf[1][ks], sc1[c]);
        if (do0) sc0[c] = mfma16(kf[c], qf[0][ks], sc0[c]);
      }
    }

    if (do0) {
      SOFTMAX_M(sc0, 0, mask0);
    }

    // V fragments from LDS
    bf16x8 vb[2][4];
#pragma unroll
    for (int ks = 0; ks < 2; ++ks)
#pragma unroll
      for (int n = 0; n < 4; ++n)
        vb[ks][n] = *reinterpret_cast<const bf16x8*>(
            Vb + (n * 16 + lr) * 128 + ((ks * 64 + lk * 16) ^ xr));

    if (do0) {
      // PV m0
#pragma unroll
      for (int ks = 0; ks < 2; ++ks) {
        bf16x8 pa = *reinterpret_cast<const bf16x8*>(
            Pb + lr * 128 + ((ks * 64 + lk * 16) ^ xr));
#pragma unroll
        for (int n = 0; n < 4; ++n) oacc[0][n] = mfma16(pa, vb[ks][n], oacc[0][n]);
      }
    }

    SOFTMAX_M(sc1, 1, mask1);
    // PV m1
#pragma unroll
    for (int ks = 0; ks < 2; ++ks) {
      bf16x8 pa = *reinterpret_cast<const bf16x8*>(
          Pb + lr * 128 + ((ks * 64 + lk * 16) ^ xr));
#pragma unroll
      for (int n = 0; n < 4; ++n) oacc[1][n] = mfma16(pa, vb[ks][n], oacc[1][n]);
    }

    __syncthreads();
    buf ^= 1;
  }
#undef SOFTMAX_M
#undef STAGE

  // epilogue: O[q][d], q = base + lk*4+r, d = h*64 + n*16 + lr
#pragma unroll
  for (int m = 0; m < 2; ++m) {
    const int base = (m == 0) ? qlo0 : qhi0;
    float iv[4];
#pragma unroll
    for (int r = 0; r < 4; ++r)
      iv[r] = 1.f / __shfl(l_i[m], (lane & 48) | (lk * 4 + r), 64);
#pragma unroll
    for (int n = 0; n < 4; ++n)
#pragma unroll
      for (int r = 0; r < 4; ++r) {
        int row = base + lk * 4 + r;
        int col = h * 64 + n * 16 + lr;
        ao[((size_t)b * S_LEN + row) * DMODEL + col] = f2bf(oacc[m][n][r] * iv[r]);
      }
  }
}

// ---------------- launch ----------------
extern "C" void kernel_launch(void* const* d_in, const int* in_sizes, int n_in,
                              void* d_out, int out_size, void* d_ws, size_t ws_size,
                              hipStream_t stream) {
  const float* x = (const float*)d_in[0];
  const float* wqkv = (const float*)d_in[1];
  const float* bqkv = (const float*)d_in[2];
  const float* wproj = (const float*)d_in[3];
  const float* bproj = (const float*)d_in[4];
  float* out = (float*)d_out;

  char* ws = (char*)d_ws;
  u16* Xb     = (u16*)(ws);                       // [8192][1024] bf16, 16 MiB
  u16* Wqkvt  = (u16*)(ws + (size_t)16777216);    // [3072][1024] bf16,  6 MiB
  u16* Wprojt = (u16*)(ws + (size_t)23068672);    // [1024][1024] bf16,  2 MiB
  u16* QKb    = (u16*)(ws + (size_t)25165824);    // [8192][2048] bf16, 32 MiB
  u16* Vt     = (u16*)(ws + (size_t)58720256);    // [64*64][2048] bf16, 16 MiB
  u16* AOb    = (u16*)(ws + (size_t)75497472);    // [8192][1024] bf16, 16 MiB

  k_f32_to_bf16<<<MROWS * DMODEL / 4 / 256, 256, 0, stream>>>(x, Xb, MROWS * DMODEL);
  k_transpose_to_bf16<<<dim3(3072 / 32, 1024 / 32), 256, 0, stream>>>(wqkv, Wqkvt, 1024, 3072);
  k_transpose_to_bf16<<<dim3(1024 / 32, 1024 / 32), 256, 0, stream>>>(wproj, Wprojt, 1024, 1024);

  // qkv GEMM: Q,K -> QKb (row stride 2048); V -> Vt transposed
  k_gemm_bt<2><<<dim3(MROWS / 128, 3072 / 128), 256, 0, stream>>>(
      Xb, Wqkvt, bqkv, QKb, nullptr, Vt, 3072, 1024);

  k_attn4<<<dim3(1024), 256, 0, stream>>>(QKb, Vt, AOb);

  k_gemm_bt<1><<<dim3(MROWS / 128, DMODEL / 128), 256, 0, stream>>>(
      AOb, Wprojt, bproj, nullptr, out, nullptr, DMODEL, 1024);
}

// Round 5
// 199.521 us; speedup vs baseline: 1.6817x; 1.2442x over previous
//
#include <hip/hip_runtime.h>

// CausalSelfAttention: B=4, S=2048, D=1024, H=16, HS=64
// bf16 MFMA everywhere, fp32 accumulate.
// attn v5: 32x32x16 MFMA, swapped operands (S^T = K Q^T, O^T = V^T P^T),
// lane-aligned softmax (q = lane&31), in-register P via cvt_pk + permlane32_swap.

typedef unsigned short u16;
typedef short bf16x8 __attribute__((ext_vector_type(8)));
typedef unsigned short u16x8 __attribute__((ext_vector_type(8)));
typedef float f32x4 __attribute__((ext_vector_type(4)));
typedef float f32x16 __attribute__((ext_vector_type(16)));

#define S_LEN 2048
#define DMODEL 1024
#define NHEAD 16
#define MROWS 8192  // B*S

// 0.25 (1/sqrt(H)) * log2(e)
#define SCALE_LOG2E 0.36067376022224085f
#define DEFER_THR 8.0f

__device__ __forceinline__ u16 f2bf(float f) {
  union { float f; unsigned u; } c; c.f = f;
  unsigned u = c.u;
  u += 0x7fffu + ((u >> 16) & 1u);  // RNE
  return (u16)(u >> 16);
}

__device__ __forceinline__ float exp2_fast(float x) {
  float r; asm("v_exp_f32 %0, %1" : "=v"(r) : "v"(x)); return r;
}

__device__ __forceinline__ unsigned cvtpk_bf16(float a, float b) {
  unsigned r;
  asm("v_cvt_pk_bf16_f32 %0, %1, %2" : "=v"(r) : "v"(a), "v"(b));
  return r;
}

// v_permlane32_swap_b32: a' = {a_lo, b_lo}, b' = {a_hi, b_hi}
__device__ __forceinline__ void plswap(unsigned& a, unsigned& b) {
  asm("v_permlane32_swap_b32 %0, %1" : "+v"(a), "+v"(b));
}

__device__ __forceinline__ f32x4 mfma16(bf16x8 a, bf16x8 b, f32x4 c) {
  return __builtin_amdgcn_mfma_f32_16x16x32_bf16(a, b, c, 0, 0, 0);
}

__device__ __forceinline__ f32x16 mfma32(bf16x8 a, bf16x8 b, f32x16 c) {
  return __builtin_amdgcn_mfma_f32_32x32x16_bf16(a, b, c, 0, 0, 0);
}

__device__ __forceinline__ void gload_lds16(const void* g, void* l) {
  __builtin_amdgcn_global_load_lds((__attribute__((address_space(1))) void*)g,
                                   (__attribute__((address_space(3))) void*)l,
                                   16, 0, 0);
}

// ---------------- conversion kernels ----------------
__global__ void k_f32_to_bf16(const float* __restrict__ in, u16* __restrict__ out, int n) {
  int i = (blockIdx.x * 256 + threadIdx.x) * 4;
  if (i < n) {
    float4 v = *reinterpret_cast<const float4*>(in + i);
    ushort4 o;
    o.x = f2bf(v.x); o.y = f2bf(v.y); o.z = f2bf(v.z); o.w = f2bf(v.w);
    *reinterpret_cast<ushort4*>(out + i) = o;
  }
}

// w[K][N] fp32 -> wt[N][K] bf16
__global__ void k_transpose_to_bf16(const float* __restrict__ in, u16* __restrict__ out,
                                    int K, int N) {
  __shared__ float t[32][33];
  int n0 = blockIdx.x * 32, k0 = blockIdx.y * 32;
  int tx = threadIdx.x & 31, ty = threadIdx.x >> 5;  // 32 x 8
#pragma unroll
  for (int i = 0; i < 32; i += 8)
    t[ty + i][tx] = in[(size_t)(k0 + ty + i) * N + n0 + tx];
  __syncthreads();
#pragma unroll
  for (int i = 0; i < 32; i += 8)
    out[(size_t)(n0 + ty + i) * K + k0 + tx] = f2bf(t[tx][ty + i]);
}

// ---------------- GEMM: C[M][N] = A[M][K] * Bt[N][K]^T + bias ----------------
// MODE 1: fp32 out (stride N).  MODE 2: qkv-split: col<2048 -> qk[row*2048+col]
// (bf16); col>=2048 -> V transposed into vt[(b*16+h)*64+d][s] (bf16).
template <int MODE>
__global__ __launch_bounds__(256) void k_gemm_bt(const u16* __restrict__ A,
                                                 const u16* __restrict__ Bt,
                                                 const float* __restrict__ bias,
                                                 u16* __restrict__ outb,
                                                 float* __restrict__ outf,
                                                 u16* __restrict__ vtout,
                                                 int N, int K) {
  __shared__ u16 As[128 * 64];
  __shared__ u16 Bs[128 * 64];
  const int tid = threadIdx.x;
  const int lane = tid & 63, wave = tid >> 6;
  const int wm = wave >> 1, wn = wave & 1;
  const int lr = lane & 15, lk = lane >> 4;
  const int m0 = blockIdx.x * 128, n0 = blockIdx.y * 128;

  f32x4 zero4 = {0.f, 0.f, 0.f, 0.f};
  f32x4 acc[4][4];
#pragma unroll
  for (int m = 0; m < 4; ++m)
#pragma unroll
    for (int n = 0; n < 4; ++n) acc[m][n] = zero4;

  const int nkt = K >> 6;
  for (int kt = 0; kt < nkt; ++kt) {
    const u16* Ag = A + (size_t)m0 * K + kt * 64;
    const u16* Bg = Bt + (size_t)n0 * K + kt * 64;
#pragma unroll
    for (int j = 0; j < 4; ++j) {
      int chunk = j * 4 + wave;
      int row = chunk * 8 + (lane >> 3);
      int cole = (lane & 7) * 8;
      gload_lds16(Ag + (size_t)row * K + cole, &As[chunk * 512]);
      gload_lds16(Bg + (size_t)row * K + cole, &Bs[chunk * 512]);
    }
    __syncthreads();
#pragma unroll
    for (int ks = 0; ks < 2; ++ks) {
      bf16x8 af[4], bfr[4];
#pragma unroll
      for (int m = 0; m < 4; ++m)
        af[m] = *reinterpret_cast<const bf16x8*>(&As[(wm * 64 + m * 16 + lr) * 64 + ks * 32 + lk * 8]);
#pragma unroll
      for (int n = 0; n < 4; ++n)
        bfr[n] = *reinterpret_cast<const bf16x8*>(&Bs[(wn * 64 + n * 16 + lr) * 64 + ks * 32 + lk * 8]);
#pragma unroll
      for (int m = 0; m < 4; ++m)
#pragma unroll
        for (int n = 0; n < 4; ++n) acc[m][n] = mfma16(af[m], bfr[n], acc[m][n]);
    }
    __syncthreads();
  }

#pragma unroll
  for (int n = 0; n < 4; ++n) {
    int col = n0 + wn * 64 + n * 16 + lr;
    float bv = bias[col];
#pragma unroll
    for (int m = 0; m < 4; ++m) {
      int rowb = m0 + wm * 64 + m * 16 + lk * 4;
      if (MODE == 1) {
#pragma unroll
        for (int r = 0; r < 4; ++r)
          outf[(size_t)(rowb + r) * N + col] = acc[m][n][r] + bv;
      } else {
        if (col < 2048) {
#pragma unroll
          for (int r = 0; r < 4; ++r)
            outb[(size_t)(rowb + r) * 2048 + col] = f2bf(acc[m][n][r] + bv);
        } else {
          int hh = (col >> 6) & 15, dd = col & 63;
          int bb = rowb >> 11, ss = rowb & 2047;
          ushort4 o;
          o.x = f2bf(acc[m][n][0] + bv);
          o.y = f2bf(acc[m][n][1] + bv);
          o.z = f2bf(acc[m][n][2] + bv);
          o.w = f2bf(acc[m][n][3] + bv);
          *reinterpret_cast<ushort4*>(
              vtout + ((size_t)(bb * 16 + hh) * 64 + dd) * 2048 + ss) = o;
        }
      }
    }
  }
}

// ---------------- flash attention v5 (32x32 MFMA) ----------------
// grid 512: bh = gid&63; qb via balance-remap. Block 256 = 4 waves.
// Wave owns 32 lo rows (tile qb*128 + w*32) and 32 hi rows (mirror).
// S^T = K.Q^T: D col = q = lane&31 -> softmax lane-aligned, 1 shfl per reduce.
// P stays in registers: cvt_pk pairs + permlane32_swap -> PV B-fragments.
// O^T = V^T.P^T accumulated with col = q; rescale/normalize per-lane scalar.
__global__ __launch_bounds__(256, 2) void k_attn5(const u16* __restrict__ qk,
                                                  const u16* __restrict__ vt,
                                                  u16* __restrict__ ao) {
  __shared__ u16 Ks[2][4096];   // [key 0..63][k 0..63], 128B rows, XOR-swizzled
  __shared__ u16 Vs[2][4096];   // [d 0..63][key 0..63], swizzled

  const int tid = threadIdx.x;
  const int lane = tid & 63, wave = tid >> 6;
  const int l31 = lane & 31, hi = lane >> 5;
  const int gid = blockIdx.x;
  const int bh = gid & 63;
  const int tq = gid >> 6;
  const int qb = (tq < 4) ? tq : 11 - tq;  // pair long+short trip counts per CU
  const int b = bh >> 4, h = bh & 15;

  const int qlo0 = qb * 128 + wave * 32;
  const int qhi0 = 1920 - qb * 128 + wave * 32;
  const int ktd_lo = qlo0 >> 6;
  const int ktd_hi = qhi0 >> 6;
  const int KTMAX = 31 - 2 * qb;
  const int qrel0 = qlo0 + l31 - ktd_lo * 64;  // masks: key_in_tile > qrel
  const int qrel1 = qhi0 + l31 - ktd_hi * 64;

  // Q fragments (B-operand): lane holds Q[q = l31][k = ks*16 + hi*8 ..+8]
  bf16x8 qf[2][4];
  {
    const u16* q0p = qk + ((size_t)b * S_LEN + qlo0 + l31) * 2048 + h * 64 + hi * 8;
    const u16* q1p = qk + ((size_t)b * S_LEN + qhi0 + l31) * 2048 + h * 64 + hi * 8;
#pragma unroll
    for (int ks = 0; ks < 4; ++ks) {
      qf[0][ks] = *reinterpret_cast<const bf16x8*>(q0p + ks * 16);
      qf[1][ks] = *reinterpret_cast<const bf16x8*>(q1p + ks * 16);
    }
  }

  // staging sources (per-lane, pre-swizzled column)
  const int swzcol = 16 * ((lane & 7) ^ (lane >> 3));
  const char* kg = (const char*)qk + ((size_t)b * S_LEN) * 4096 + 2048 + h * 128 +
                   (size_t)(lane >> 3) * 4096 + swzcol;
  const char* vg = (const char*)vt + ((size_t)bh * 64 + (lane >> 3)) * 4096 + swzcol;

#define STAGE(BUF, KT)                                                              \
  {                                                                                 \
    const char* kg_ = kg + (size_t)(KT) * 64 * 4096;                                \
    const char* vg_ = vg + (size_t)(KT) * 128;                                      \
    gload_lds16(kg_ + (size_t)(wave * 8) * 4096, &Ks[BUF][wave * 512]);             \
    gload_lds16(kg_ + (size_t)((wave + 4) * 8) * 4096, &Ks[BUF][(wave + 4) * 512]); \
    gload_lds16(vg_ + (size_t)(wave * 8) * 4096, &Vs[BUF][wave * 512]);             \
    gload_lds16(vg_ + (size_t)((wave + 4) * 8) * 4096, &Vs[BUF][(wave + 4) * 512]); \
  }

  f32x16 oT[2][2];  // [m][d-block]: O^T[d = kbd*32 + row(reg,hi)][q = l31]
#pragma unroll
  for (int m = 0; m < 2; ++m)
#pragma unroll
    for (int kb = 0; kb < 2; ++kb)
#pragma unroll
      for (int g = 0; g < 16; ++g) oT[m][kb][g] = 0.f;
  float m_i[2] = {-INFINITY, -INFINITY};
  float l_i[2] = {0.f, 0.f};

  const int rsw = (l31 & 7) << 4;  // LDS row-XOR for rows = kb*32 + l31

  // softmax m-group M: scores SC[2] (f32x16), key = kb*32 + (g&3)+8*(g>>2)+4*hi
  // builds PV B-frags into FR[4] (uint4-as-bf16x8)
#define SM32(SC, M, MASKED, QREL, FR)                                           \
  {                                                                             \
    float s_[2][16];                                                            \
    float mx_ = -INFINITY;                                                      \
    _Pragma("unroll") for (int kb = 0; kb < 2; ++kb)                            \
      _Pragma("unroll") for (int g = 0; g < 16; ++g) {                          \
        float v_ = SC[kb][g] * SCALE_LOG2E;                                     \
        if (MASKED) {                                                           \
          int key_ = kb * 32 + (g & 3) + ((g >> 2) << 3) + hi * 4;              \
          if (key_ > (QREL)) v_ = -INFINITY;                                    \
        }                                                                       \
        s_[kb][g] = v_;                                                         \
        mx_ = fmaxf(mx_, v_);                                                   \
      }                                                                         \
    mx_ = fmaxf(mx_, __shfl_xor(mx_, 32, 64));                                  \
    if (__any(mx_ > m_i[M] + DEFER_THR)) {                                      \
      float mn_ = fmaxf(m_i[M], mx_);                                           \
      float c_ = exp2_fast(m_i[M] - mn_);                                       \
      m_i[M] = mn_;                                                             \
      l_i[M] *= c_;                                                             \
      _Pragma("unroll") for (int kb = 0; kb < 2; ++kb)                          \
        _Pragma("unroll") for (int g = 0; g < 16; ++g) oT[M][kb][g] *= c_;      \
    }                                                                           \
    float rs_ = 0.f;                                                            \
    unsigned pk_[8][2];                                                         \
    _Pragma("unroll") for (int kb = 0; kb < 2; ++kb)                            \
      _Pragma("unroll") for (int s = 0; s < 4; ++s) {                           \
        float p0_ = exp2_fast(s_[kb][s * 4 + 0] - m_i[M]);                      \
        float p1_ = exp2_fast(s_[kb][s * 4 + 1] - m_i[M]);                      \
        float p2_ = exp2_fast(s_[kb][s * 4 + 2] - m_i[M]);                      \
        float p3_ = exp2_fast(s_[kb][s * 4 + 3] - m_i[M]);                      \
        rs_ += (p0_ + p1_) + (p2_ + p3_);                                       \
        pk_[kb * 4 + s][0] = cvtpk_bf16(p0_, p1_);                              \
        pk_[kb * 4 + s][1] = cvtpk_bf16(p2_, p3_);                              \
      }                                                                         \
    rs_ += __shfl_xor(rs_, 32, 64);                                             \
    l_i[M] += rs_;                                                              \
    _Pragma("unroll") for (int t = 0; t < 4; ++t) {                             \
      unsigned a0_ = pk_[2 * t][0], b0_ = pk_[2 * t + 1][0];                    \
      unsigned a1_ = pk_[2 * t][1], b1_ = pk_[2 * t + 1][1];                    \
      plswap(a0_, b0_);                                                         \
      plswap(a1_, b1_);                                                         \
      FR[t][0] = a0_; FR[t][1] = a1_; FR[t][2] = b0_; FR[t][3] = b1_;           \
    }                                                                           \
  }

  STAGE(0, 0);
  __syncthreads();
  int buf = 0;

  for (int kt = 0; kt <= KTMAX; ++kt) {
    if (kt < KTMAX) STAGE(buf ^ 1, kt + 1);

    const char* Kb = (const char*)&Ks[buf][0];
    const char* Vb = (const char*)&Vs[buf][0];
    const bool lo_act = (kt <= ktd_lo);
    const bool hi_act = (kt <= ktd_hi);
    const bool mask0 = (kt == ktd_lo), mask1 = (kt == ktd_hi);

    // K fragments (A-operand): K[key = kb*32 + l31][k = ks*16 + hi*8]
    bf16x8 kf[2][4];
#pragma unroll
    for (int kb = 0; kb < 2; ++kb)
#pragma unroll
      for (int ks = 0; ks < 4; ++ks)
        kf[kb][ks] = *reinterpret_cast<const bf16x8*>(
            Kb + (kb * 32 + l31) * 128 + ((ks * 32 + hi * 16) ^ rsw));

    // S^T = K.Q^T
    f32x16 sc0[2], sc1[2];
#pragma unroll
    for (int kb = 0; kb < 2; ++kb) {
      if (hi_act) {
        sc1[kb] = mfma32(kf[kb][0], qf[1][0], f32x16{});
#pragma unroll
        for (int ks = 1; ks < 4; ++ks) sc1[kb] = mfma32(kf[kb][ks], qf[1][ks], sc1[kb]);
      }
      if (lo_act) {
        sc0[kb] = mfma32(kf[kb][0], qf[0][0], f32x16{});
#pragma unroll
        for (int ks = 1; ks < 4; ++ks) sc0[kb] = mfma32(kf[kb][ks], qf[0][ks], sc0[kb]);
      }
    }

    // V fragments (A-operand): V^T[d = kbd*32 + l31][key = t*16 + hi*8]
    bf16x8 vf[2][4];
#pragma unroll
    for (int kbd = 0; kbd < 2; ++kbd)
#pragma unroll
      for (int t = 0; t < 4; ++t)
        vf[kbd][t] = *reinterpret_cast<const bf16x8*>(
            Vb + (kbd * 32 + l31) * 128 + ((t * 32 + hi * 16) ^ rsw));

    if (lo_act) {
      unsigned fr0[4][4];
      SM32(sc0, 0, mask0, qrel0, fr0);
#pragma unroll
      for (int t = 0; t < 4; ++t) {
        bf16x8 pb = *reinterpret_cast<const bf16x8*>(&fr0[t][0]);
        oT[0][0] = mfma32(vf[0][t], pb, oT[0][0]);
        oT[0][1] = mfma32(vf[1][t], pb, oT[0][1]);
      }
    }
    if (hi_act) {
      unsigned fr1[4][4];
      SM32(sc1, 1, mask1, qrel1, fr1);
#pragma unroll
      for (int t = 0; t < 4; ++t) {
        bf16x8 pb = *reinterpret_cast<const bf16x8*>(&fr1[t][0]);
        oT[1][0] = mfma32(vf[0][t], pb, oT[1][0]);
        oT[1][1] = mfma32(vf[1][t], pb, oT[1][1]);
      }
    }

    __syncthreads();
    buf ^= 1;
  }
#undef SM32
#undef STAGE

  // epilogue: out row = q (all 32 d-values per lane in one row)
#pragma unroll
  for (int m = 0; m < 2; ++m) {
    const int qbase = (m == 0) ? qlo0 : qhi0;
    float inv = 1.f / l_i[m];
    u16* orow = ao + ((size_t)b * S_LEN + qbase + l31) * DMODEL + h * 64 + hi * 4;
#pragma unroll
    for (int kbd = 0; kbd < 2; ++kbd)
#pragma unroll
      for (int s = 0; s < 4; ++s) {
        unsigned w0 = cvtpk_bf16(oT[m][kbd][s * 4 + 0] * inv, oT[m][kbd][s * 4 + 1] * inv);
        unsigned w1 = cvtpk_bf16(oT[m][kbd][s * 4 + 2] * inv, oT[m][kbd][s * 4 + 3] * inv);
        *reinterpret_cast<unsigned*>(orow + kbd * 32 + s * 8) = w0;
        *reinterpret_cast<unsigned*>(orow + kbd * 32 + s * 8 + 2) = w1;
      }
  }
}

// ---------------- launch ----------------
extern "C" void kernel_launch(void* const* d_in, const int* in_sizes, int n_in,
                              void* d_out, int out_size, void* d_ws, size_t ws_size,
                              hipStream_t stream) {
  const float* x = (const float*)d_in[0];
  const float* wqkv = (const float*)d_in[1];
  const float* bqkv = (const float*)d_in[2];
  const float* wproj = (const float*)d_in[3];
  const float* bproj = (const float*)d_in[4];
  float* out = (float*)d_out;

  char* ws = (char*)d_ws;
  u16* Xb     = (u16*)(ws);                       // [8192][1024] bf16, 16 MiB
  u16* Wqkvt  = (u16*)(ws + (size_t)16777216);    // [3072][1024] bf16,  6 MiB
  u16* Wprojt = (u16*)(ws + (size_t)23068672);    // [1024][1024] bf16,  2 MiB
  u16* QKb    = (u16*)(ws + (size_t)25165824);    // [8192][2048] bf16, 32 MiB
  u16* Vt     = (u16*)(ws + (size_t)58720256);    // [64*64][2048] bf16, 16 MiB
  u16* AOb    = (u16*)(ws + (size_t)75497472);    // [8192][1024] bf16, 16 MiB

  k_f32_to_bf16<<<MROWS * DMODEL / 4 / 256, 256, 0, stream>>>(x, Xb, MROWS * DMODEL);
  k_transpose_to_bf16<<<dim3(3072 / 32, 1024 / 32), 256, 0, stream>>>(wqkv, Wqkvt, 1024, 3072);
  k_transpose_to_bf16<<<dim3(1024 / 32, 1024 / 32), 256, 0, stream>>>(wproj, Wprojt, 1024, 1024);

  // qkv GEMM: Q,K -> QKb (row stride 2048); V -> Vt transposed
  k_gemm_bt<2><<<dim3(MROWS / 128, 3072 / 128), 256, 0, stream>>>(
      Xb, Wqkvt, bqkv, QKb, nullptr, Vt, 3072, 1024);

  k_attn5<<<dim3(512), 256, 0, stream>>>(QKb, Vt, AOb);

  k_gemm_bt<1><<<dim3(MROWS / 128, DMODEL / 128), 256, 0, stream>>>(
      AOb, Wprojt, bproj, nullptr, out, nullptr, DMODEL, 1024);
}

// Round 6
// 184.798 us; speedup vs baseline: 1.8156x; 1.0797x over previous
//
#include <hip/hip_runtime.h>

// CausalSelfAttention: B=4, S=2048, D=1024, H=16, HS=64
// bf16 MFMA everywhere, fp32 accumulate.
// GEMMs: 256x128 tile, 8 waves, k-split half-tile pipeline with counted
// vmcnt(3), raw barriers, swizzled conflict-free LDS (T2/T3/T4/T5).
// attn v5: 32x32 MFMA, swapped operands, in-register softmax (unchanged).

typedef unsigned short u16;
typedef short bf16x8 __attribute__((ext_vector_type(8)));
typedef unsigned short u16x8 __attribute__((ext_vector_type(8)));
typedef float f32x4 __attribute__((ext_vector_type(4)));
typedef float f32x16 __attribute__((ext_vector_type(16)));

#define S_LEN 2048
#define DMODEL 1024
#define NHEAD 16
#define MROWS 8192  // B*S

// 0.25 (1/sqrt(H)) * log2(e)
#define SCALE_LOG2E 0.36067376022224085f
#define DEFER_THR 8.0f

__device__ __forceinline__ u16 f2bf(float f) {
  union { float f; unsigned u; } c; c.f = f;
  unsigned u = c.u;
  u += 0x7fffu + ((u >> 16) & 1u);  // RNE
  return (u16)(u >> 16);
}

__device__ __forceinline__ float exp2_fast(float x) {
  float r; asm("v_exp_f32 %0, %1" : "=v"(r) : "v"(x)); return r;
}

__device__ __forceinline__ unsigned cvtpk_bf16(float a, float b) {
  unsigned r;
  asm("v_cvt_pk_bf16_f32 %0, %1, %2" : "=v"(r) : "v"(a), "v"(b));
  return r;
}

// v_permlane32_swap_b32: a' = {a_lo, b_lo}, b' = {a_hi, b_hi}
__device__ __forceinline__ void plswap(unsigned& a, unsigned& b) {
  asm("v_permlane32_swap_b32 %0, %1" : "+v"(a), "+v"(b));
}

__device__ __forceinline__ f32x4 mfma16(bf16x8 a, bf16x8 b, f32x4 c) {
  return __builtin_amdgcn_mfma_f32_16x16x32_bf16(a, b, c, 0, 0, 0);
}

__device__ __forceinline__ f32x16 mfma32(bf16x8 a, bf16x8 b, f32x16 c) {
  return __builtin_amdgcn_mfma_f32_32x32x16_bf16(a, b, c, 0, 0, 0);
}

__device__ __forceinline__ void gload_lds16(const void* g, void* l) {
  __builtin_amdgcn_global_load_lds((__attribute__((address_space(1))) void*)g,
                                   (__attribute__((address_space(3))) void*)l,
                                   16, 0, 0);
}

// ---------------- conversion kernels ----------------
__global__ void k_f32_to_bf16(const float* __restrict__ in, u16* __restrict__ out, int n) {
  int i = (blockIdx.x * 256 + threadIdx.x) * 4;
  if (i < n) {
    float4 v = *reinterpret_cast<const float4*>(in + i);
    ushort4 o;
    o.x = f2bf(v.x); o.y = f2bf(v.y); o.z = f2bf(v.z); o.w = f2bf(v.w);
    *reinterpret_cast<ushort4*>(out + i) = o;
  }
}

// w[K][N] fp32 -> wt[N][K] bf16
__global__ void k_transpose_to_bf16(const float* __restrict__ in, u16* __restrict__ out,
                                    int K, int N) {
  __shared__ float t[32][33];
  int n0 = blockIdx.x * 32, k0 = blockIdx.y * 32;
  int tx = threadIdx.x & 31, ty = threadIdx.x >> 5;  // 32 x 8
#pragma unroll
  for (int i = 0; i < 32; i += 8)
    t[ty + i][tx] = in[(size_t)(k0 + ty + i) * N + n0 + tx];
  __syncthreads();
#pragma unroll
  for (int i = 0; i < 32; i += 8)
    out[(size_t)(n0 + ty + i) * K + k0 + tx] = f2bf(t[tx][ty + i]);
}

// ---------------- GEMM v2: C[M][N] = A[M][K] * Bt[N][K]^T + bias ----------------
// 256x128 tile, 512 threads (8 waves: 4 wr x 2 wc), BK=64 as two k-halves.
// Pipeline: 2 LDS buffers, counted vmcnt(3), 1 barrier/phase, setprio MFMA.
// LDS rows 64B, chunk swizzle c ^= (row>>1)&3 (both stage-source and read).
// MODE 1: fp32 out.  MODE 2: qkv-split (col<2048 -> qk bf16; else V -> vt^T).
template <int MODE>
__global__ __launch_bounds__(512, 1) void k_gemm8(const u16* __restrict__ A,
                                                  const u16* __restrict__ Bt,
                                                  const float* __restrict__ bias,
                                                  u16* __restrict__ outb,
                                                  float* __restrict__ outf,
                                                  u16* __restrict__ vtout,
                                                  int N, int K) {
  __shared__ u16 As[2][2][256 * 32];  // [buf][khalf][row][32 k-elems], 64B rows
  __shared__ u16 Bs[2][2][128 * 32];

  const int tid = threadIdx.x;
  const int lane = tid & 63, wave = tid >> 6;
  const int wr = wave >> 1, wc = wave & 1;
  const int lr = lane & 15, lk = lane >> 4;
  const int m0 = blockIdx.x * 256, n0 = blockIdx.y * 128;
  const size_t Kb = (size_t)K * 2;  // row stride bytes

  // staging source bases: row = tid>>2 (+128 for A issue 1), chunk pre-swizzled
  const int csw = ((tid & 3) ^ ((tid >> 3) & 3)) * 16;
  const char* Asrc0 = (const char*)A + (size_t)(m0 + (tid >> 2)) * Kb + csw;
  const char* Asrc1 = Asrc0 + 128 * Kb;
  const char* Bsrc0 = (const char*)Bt + (size_t)(n0 + (tid >> 2)) * Kb + csw;

#define STAGE_KH(BUFX, KH, T)                                                  \
  {                                                                            \
    const size_t ko_ = (size_t)(T) * 128 + (KH) * 64;                          \
    gload_lds16(Asrc0 + ko_, &As[BUFX][KH][(size_t)tid * 8]);                  \
    gload_lds16(Asrc1 + ko_, &As[BUFX][KH][((size_t)tid + 512) * 8]);          \
    gload_lds16(Bsrc0 + ko_, &Bs[BUFX][KH][(size_t)tid * 8]);                  \
  }

  f32x4 zero4 = {0.f, 0.f, 0.f, 0.f};
  f32x4 acc[4][4];
#pragma unroll
  for (int m = 0; m < 4; ++m)
#pragma unroll
    for (int n = 0; n < 4; ++n) acc[m][n] = zero4;

  const int slotsw = (lr >> 1) & 3;  // read-side swizzle: chunk = lk ^ slotsw

  // one phase: wait own k-half landed (keep next in flight), barrier, read
  // frags, stage same k-half of tile T+1, MFMA.
#define PHASE(BUFX, KH, T, DOSTAGE, VMZERO)                                    \
  {                                                                            \
    if (VMZERO) asm volatile("s_waitcnt vmcnt(0)" ::: "memory");               \
    else        asm volatile("s_waitcnt vmcnt(3)" ::: "memory");               \
    __builtin_amdgcn_s_barrier();                                              \
    __builtin_amdgcn_sched_barrier(0);                                         \
    bf16x8 af[4], bfr[4];                                                      \
    _Pragma("unroll") for (int m = 0; m < 4; ++m)                              \
        af[m] = *reinterpret_cast<const bf16x8*>(                              \
            &As[BUFX][KH][(wr * 64 + m * 16 + lr) * 32 + ((lk ^ slotsw) * 8)]);\
    _Pragma("unroll") for (int n = 0; n < 4; ++n)                              \
        bfr[n] = *reinterpret_cast<const bf16x8*>(                             \
            &Bs[BUFX][KH][(wc * 64 + n * 16 + lr) * 32 + ((lk ^ slotsw) * 8)]);\
    if (DOSTAGE) STAGE_KH((BUFX) ^ 1, KH, (T) + 1);                            \
    __builtin_amdgcn_sched_barrier(0);                                         \
    __builtin_amdgcn_s_setprio(1);                                             \
    _Pragma("unroll") for (int m = 0; m < 4; ++m)                              \
        _Pragma("unroll") for (int n = 0; n < 4; ++n)                          \
            acc[m][n] = mfma16(af[m], bfr[n], acc[m][n]);                      \
    __builtin_amdgcn_s_setprio(0);                                             \
  }

  const int nkt = K >> 6;  // 16
  // prologue: tile 0, both k-halves (issue order defines vmcnt counting)
  STAGE_KH(0, 0, 0);
  STAGE_KH(0, 1, 0);

  for (int t = 0; t < nkt - 1; ++t) {
    const int buf = t & 1;
    PHASE(buf, 0, t, 1, 0);
    PHASE(buf, 1, t, 1, 0);
  }
  {
    const int buf = (nkt - 1) & 1;
    PHASE(buf, 0, nkt - 1, 0, 0);
    PHASE(buf, 1, nkt - 1, 0, 1);
  }
#undef PHASE
#undef STAGE_KH

  // epilogue
#pragma unroll
  for (int n = 0; n < 4; ++n) {
    int col = n0 + wc * 64 + n * 16 + lr;
    float bv = bias[col];
#pragma unroll
    for (int m = 0; m < 4; ++m) {
      int rowb = m0 + wr * 64 + m * 16 + lk * 4;
      if (MODE == 1) {
#pragma unroll
        for (int r = 0; r < 4; ++r)
          outf[(size_t)(rowb + r) * N + col] = acc[m][n][r] + bv;
      } else {
        if (col < 2048) {
#pragma unroll
          for (int r = 0; r < 4; ++r)
            outb[(size_t)(rowb + r) * 2048 + col] = f2bf(acc[m][n][r] + bv);
        } else {
          int hh = (col >> 6) & 15, dd = col & 63;
          int bb = rowb >> 11, ss = rowb & 2047;
          ushort4 o;
          o.x = f2bf(acc[m][n][0] + bv);
          o.y = f2bf(acc[m][n][1] + bv);
          o.z = f2bf(acc[m][n][2] + bv);
          o.w = f2bf(acc[m][n][3] + bv);
          *reinterpret_cast<ushort4*>(
              vtout + ((size_t)(bb * 16 + hh) * 64 + dd) * 2048 + ss) = o;
        }
      }
    }
  }
}

// ---------------- flash attention v5 (32x32 MFMA) ---------------- (unchanged)
__global__ __launch_bounds__(256, 2) void k_attn5(const u16* __restrict__ qk,
                                                  const u16* __restrict__ vt,
                                                  u16* __restrict__ ao) {
  __shared__ u16 Ks[2][4096];   // [key 0..63][k 0..63], 128B rows, XOR-swizzled
  __shared__ u16 Vs[2][4096];   // [d 0..63][key 0..63], swizzled

  const int tid = threadIdx.x;
  const int lane = tid & 63, wave = tid >> 6;
  const int l31 = lane & 31, hi = lane >> 5;
  const int gid = blockIdx.x;
  const int bh = gid & 63;
  const int tq = gid >> 6;
  const int qb = (tq < 4) ? tq : 11 - tq;  // pair long+short trip counts per CU
  const int b = bh >> 4, h = bh & 15;

  const int qlo0 = qb * 128 + wave * 32;
  const int qhi0 = 1920 - qb * 128 + wave * 32;
  const int ktd_lo = qlo0 >> 6;
  const int ktd_hi = qhi0 >> 6;
  const int KTMAX = 31 - 2 * qb;
  const int qrel0 = qlo0 + l31 - ktd_lo * 64;
  const int qrel1 = qhi0 + l31 - ktd_hi * 64;

  bf16x8 qf[2][4];
  {
    const u16* q0p = qk + ((size_t)b * S_LEN + qlo0 + l31) * 2048 + h * 64 + hi * 8;
    const u16* q1p = qk + ((size_t)b * S_LEN + qhi0 + l31) * 2048 + h * 64 + hi * 8;
#pragma unroll
    for (int ks = 0; ks < 4; ++ks) {
      qf[0][ks] = *reinterpret_cast<const bf16x8*>(q0p + ks * 16);
      qf[1][ks] = *reinterpret_cast<const bf16x8*>(q1p + ks * 16);
    }
  }

  const int swzcol = 16 * ((lane & 7) ^ (lane >> 3));
  const char* kg = (const char*)qk + ((size_t)b * S_LEN) * 4096 + 2048 + h * 128 +
                   (size_t)(lane >> 3) * 4096 + swzcol;
  const char* vg = (const char*)vt + ((size_t)bh * 64 + (lane >> 3)) * 4096 + swzcol;

#define STAGE(BUF, KT)                                                              \
  {                                                                                 \
    const char* kg_ = kg + (size_t)(KT) * 64 * 4096;                                \
    const char* vg_ = vg + (size_t)(KT) * 128;                                      \
    gload_lds16(kg_ + (size_t)(wave * 8) * 4096, &Ks[BUF][wave * 512]);             \
    gload_lds16(kg_ + (size_t)((wave + 4) * 8) * 4096, &Ks[BUF][(wave + 4) * 512]); \
    gload_lds16(vg_ + (size_t)(wave * 8) * 4096, &Vs[BUF][wave * 512]);             \
    gload_lds16(vg_ + (size_t)((wave + 4) * 8) * 4096, &Vs[BUF][(wave + 4) * 512]); \
  }

  f32x16 oT[2][2];
#pragma unroll
  for (int m = 0; m < 2; ++m)
#pragma unroll
    for (int kb = 0; kb < 2; ++kb)
#pragma unroll
      for (int g = 0; g < 16; ++g) oT[m][kb][g] = 0.f;
  float m_i[2] = {-INFINITY, -INFINITY};
  float l_i[2] = {0.f, 0.f};

  const int rsw = (l31 & 7) << 4;

#define SM32(SC, M, MASKED, QREL, FR)                                           \
  {                                                                             \
    float s_[2][16];                                                            \
    float mx_ = -INFINITY;                                                      \
    _Pragma("unroll") for (int kb = 0; kb < 2; ++kb)                            \
      _Pragma("unroll") for (int g = 0; g < 16; ++g) {                          \
        float v_ = SC[kb][g] * SCALE_LOG2E;                                     \
        if (MASKED) {                                                           \
          int key_ = kb * 32 + (g & 3) + ((g >> 2) << 3) + hi * 4;              \
          if (key_ > (QREL)) v_ = -INFINITY;                                    \
        }                                                                       \
        s_[kb][g] = v_;                                                         \
        mx_ = fmaxf(mx_, v_);                                                   \
      }                                                                         \
    mx_ = fmaxf(mx_, __shfl_xor(mx_, 32, 64));                                  \
    if (__any(mx_ > m_i[M] + DEFER_THR)) {                                      \
      float mn_ = fmaxf(m_i[M], mx_);                                           \
      float c_ = exp2_fast(m_i[M] - mn_);                                       \
      m_i[M] = mn_;                                                             \
      l_i[M] *= c_;                                                             \
      _Pragma("unroll") for (int kb = 0; kb < 2; ++kb)                          \
        _Pragma("unroll") for (int g = 0; g < 16; ++g) oT[M][kb][g] *= c_;      \
    }                                                                           \
    float rs_ = 0.f;                                                            \
    unsigned pk_[8][2];                                                         \
    _Pragma("unroll") for (int kb = 0; kb < 2; ++kb)                            \
      _Pragma("unroll") for (int s = 0; s < 4; ++s) {                           \
        float p0_ = exp2_fast(s_[kb][s * 4 + 0] - m_i[M]);                      \
        float p1_ = exp2_fast(s_[kb][s * 4 + 1] - m_i[M]);                      \
        float p2_ = exp2_fast(s_[kb][s * 4 + 2] - m_i[M]);                      \
        float p3_ = exp2_fast(s_[kb][s * 4 + 3] - m_i[M]);                      \
        rs_ += (p0_ + p1_) + (p2_ + p3_);                                       \
        pk_[kb * 4 + s][0] = cvtpk_bf16(p0_, p1_);                              \
        pk_[kb * 4 + s][1] = cvtpk_bf16(p2_, p3_);                              \
      }                                                                         \
    rs_ += __shfl_xor(rs_, 32, 64);                                             \
    l_i[M] += rs_;                                                              \
    _Pragma("unroll") for (int t = 0; t < 4; ++t) {                             \
      unsigned a0_ = pk_[2 * t][0], b0_ = pk_[2 * t + 1][0];                    \
      unsigned a1_ = pk_[2 * t][1], b1_ = pk_[2 * t + 1][1];                    \
      plswap(a0_, b0_);                                                         \
      plswap(a1_, b1_);                                                         \
      FR[t][0] = a0_; FR[t][1] = a1_; FR[t][2] = b0_; FR[t][3] = b1_;           \
    }                                                                           \
  }

  STAGE(0, 0);
  __syncthreads();
  int buf = 0;

  for (int kt = 0; kt <= KTMAX; ++kt) {
    if (kt < KTMAX) STAGE(buf ^ 1, kt + 1);

    const char* Kb = (const char*)&Ks[buf][0];
    const char* Vb = (const char*)&Vs[buf][0];
    const bool lo_act = (kt <= ktd_lo);
    const bool hi_act = (kt <= ktd_hi);
    const bool mask0 = (kt == ktd_lo), mask1 = (kt == ktd_hi);

    bf16x8 kf[2][4];
#pragma unroll
    for (int kb = 0; kb < 2; ++kb)
#pragma unroll
      for (int ks = 0; ks < 4; ++ks)
        kf[kb][ks] = *reinterpret_cast<const bf16x8*>(
            Kb + (kb * 32 + l31) * 128 + ((ks * 32 + hi * 16) ^ rsw));

    f32x16 sc0[2], sc1[2];
#pragma unroll
    for (int kb = 0; kb < 2; ++kb) {
      if (hi_act) {
        sc1[kb] = mfma32(kf[kb][0], qf[1][0], f32x16{});
#pragma unroll
        for (int ks = 1; ks < 4; ++ks) sc1[kb] = mfma32(kf[kb][ks], qf[1][ks], sc1[kb]);
      }
      if (lo_act) {
        sc0[kb] = mfma32(kf[kb][0], qf[0][0], f32x16{});
#pragma unroll
        for (int ks = 1; ks < 4; ++ks) sc0[kb] = mfma32(kf[kb][ks], qf[0][ks], sc0[kb]);
      }
    }

    bf16x8 vf[2][4];
#pragma unroll
    for (int kbd = 0; kbd < 2; ++kbd)
#pragma unroll
      for (int t = 0; t < 4; ++t)
        vf[kbd][t] = *reinterpret_cast<const bf16x8*>(
            Vb + (kbd * 32 + l31) * 128 + ((t * 32 + hi * 16) ^ rsw));

    if (lo_act) {
      unsigned fr0[4][4];
      SM32(sc0, 0, mask0, qrel0, fr0);
#pragma unroll
      for (int t = 0; t < 4; ++t) {
        bf16x8 pb = *reinterpret_cast<const bf16x8*>(&fr0[t][0]);
        oT[0][0] = mfma32(vf[0][t], pb, oT[0][0]);
        oT[0][1] = mfma32(vf[1][t], pb, oT[0][1]);
      }
    }
    if (hi_act) {
      unsigned fr1[4][4];
      SM32(sc1, 1, mask1, qrel1, fr1);
#pragma unroll
      for (int t = 0; t < 4; ++t) {
        bf16x8 pb = *reinterpret_cast<const bf16x8*>(&fr1[t][0]);
        oT[1][0] = mfma32(vf[0][t], pb, oT[1][0]);
        oT[1][1] = mfma32(vf[1][t], pb, oT[1][1]);
      }
    }

    __syncthreads();
    buf ^= 1;
  }
#undef SM32
#undef STAGE

#pragma unroll
  for (int m = 0; m < 2; ++m) {
    const int qbase = (m == 0) ? qlo0 : qhi0;
    float inv = 1.f / l_i[m];
    u16* orow = ao + ((size_t)b * S_LEN + qbase + l31) * DMODEL + h * 64 + hi * 4;
#pragma unroll
    for (int kbd = 0; kbd < 2; ++kbd)
#pragma unroll
      for (int s = 0; s < 4; ++s) {
        unsigned w0 = cvtpk_bf16(oT[m][kbd][s * 4 + 0] * inv, oT[m][kbd][s * 4 + 1] * inv);
        unsigned w1 = cvtpk_bf16(oT[m][kbd][s * 4 + 2] * inv, oT[m][kbd][s * 4 + 3] * inv);
        *reinterpret_cast<unsigned*>(orow + kbd * 32 + s * 8) = w0;
        *reinterpret_cast<unsigned*>(orow + kbd * 32 + s * 8 + 2) = w1;
      }
  }
}

// ---------------- launch ----------------
extern "C" void kernel_launch(void* const* d_in, const int* in_sizes, int n_in,
                              void* d_out, int out_size, void* d_ws, size_t ws_size,
                              hipStream_t stream) {
  const float* x = (const float*)d_in[0];
  const float* wqkv = (const float*)d_in[1];
  const float* bqkv = (const float*)d_in[2];
  const float* wproj = (const float*)d_in[3];
  const float* bproj = (const float*)d_in[4];
  float* out = (float*)d_out;

  char* ws = (char*)d_ws;
  u16* Xb     = (u16*)(ws);                       // [8192][1024] bf16, 16 MiB
  u16* Wqkvt  = (u16*)(ws + (size_t)16777216);    // [3072][1024] bf16,  6 MiB
  u16* Wprojt = (u16*)(ws + (size_t)23068672);    // [1024][1024] bf16,  2 MiB
  u16* QKb    = (u16*)(ws + (size_t)25165824);    // [8192][2048] bf16, 32 MiB
  u16* Vt     = (u16*)(ws + (size_t)58720256);    // [64*64][2048] bf16, 16 MiB
  u16* AOb    = (u16*)(ws + (size_t)75497472);    // [8192][1024] bf16, 16 MiB

  k_f32_to_bf16<<<MROWS * DMODEL / 4 / 256, 256, 0, stream>>>(x, Xb, MROWS * DMODEL);
  k_transpose_to_bf16<<<dim3(3072 / 32, 1024 / 32), 256, 0, stream>>>(wqkv, Wqkvt, 1024, 3072);
  k_transpose_to_bf16<<<dim3(1024 / 32, 1024 / 32), 256, 0, stream>>>(wproj, Wprojt, 1024, 1024);

  // qkv GEMM: Q,K -> QKb (row stride 2048); V -> Vt transposed
  k_gemm8<2><<<dim3(MROWS / 256, 3072 / 128), 512, 0, stream>>>(
      Xb, Wqkvt, bqkv, QKb, nullptr, Vt, 3072, 1024);

  k_attn5<<<dim3(512), 256, 0, stream>>>(QKb, Vt, AOb);

  k_gemm8<1><<<dim3(MROWS / 256, DMODEL / 128), 512, 0, stream>>>(
      AOb, Wprojt, bproj, nullptr, out, nullptr, DMODEL, 1024);
}